// Round 1
// baseline (2772.039 us; speedup 1.0000x reference)
//
#include <hip/hip_runtime.h>

#define NPTS 2048
#define NB   16

// eps = 0.01, log-domain Sinkhorn in base-2.
// R = 1/(eps*ln2); TWO_R = 2R; EPS_LN2 = eps*ln2; EPS_LOGMARG = eps * (-ln N)
__device__ __constant__ float c_dummy; // keep compiler happy if unused
constexpr float K_R          = 144.26950408889634f;
constexpr float K_TWO_R      = 288.53900817779268f;
constexpr float K_EPS_LN2    = 0.0069314718055994531f;
constexpr float K_EPS_LOGMRG = -0.076246189861593985f; // 0.01 * (-ln 2048)

// ---------------------------------------------------------------- prep ------
__global__ __launch_bounds__(256) void prep_kernel(
    const float* __restrict__ x, const float* __restrict__ y,
    float4* __restrict__ px, float4* __restrict__ py, float* __restrict__ g)
{
    int idx = blockIdx.x * 256 + threadIdx.x;
    if (idx >= NB * NPTS) return;
    float x0 = x[idx*3+0], x1 = x[idx*3+1], x2 = x[idx*3+2];
    px[idx] = make_float4(x0, x1, x2, fmaf(x0,x0, fmaf(x1,x1, x2*x2)));
    float y0 = y[idx*3+0], y1 = y[idx*3+1], y2 = y[idx*3+2];
    py[idx] = make_float4(y0, y1, y2, fmaf(y0,y0, fmaf(y1,y1, y2*y2)));
    g[idx] = 0.0f;
}

// ------------------------------------------------------------ half step -----
// dual_out[i] = eps*log(1/N) + |p_row_i|^2 - eps*ln2 * log2( sum_j 2^{w2_ij} )
// w2_ij = ( (dual_in_j - |p_col_j|^2) + 2 p_row_i . p_col_j ) / (eps*ln2)
// Grid: 512 wgs (32 per batch), 256 threads. 64 rows/wg, 4-way j split.
__global__ __launch_bounds__(256) void half_step(
    const float4* __restrict__ pcol, const float* __restrict__ dual_in,
    const float4* __restrict__ prow, float* __restrict__ dual_out)
{
    __shared__ float4 ld[NPTS];     // (y*2R, a2) packed
    __shared__ float2 red[256];

    const int w     = blockIdx.x;
    const int b     = w >> 5;
    const int chunk = w & 31;
    const int tid   = threadIdx.x;

    const float4* pc = pcol    + b * NPTS;
    const float*  di = dual_in + b * NPTS;

    for (int k = tid; k < NPTS; k += 256) {
        float4 p = pc[k];
        float a2 = (di[k] - p.w) * K_R;
        ld[k] = make_float4(p.x * K_TWO_R, p.y * K_TWO_R, p.z * K_TWO_R, a2);
    }
    __syncthreads();

    const int r   = tid & 63;
    const int q   = tid >> 6;
    const int row = chunk * 64 + r;
    const float4 xi = prow[b * NPTS + row];

    float m = -3.0e38f;
    float s = 0.0f;
    const int j0 = q * 512;
    for (int j = j0; j < j0 + 512; j += 8) {
        float w2[8];
        #pragma unroll
        for (int k = 0; k < 8; ++k) {
            float4 yj = ld[j + k];
            w2[k] = fmaf(yj.x, xi.x, fmaf(yj.y, xi.y, fmaf(yj.z, xi.z, yj.w)));
        }
        float cm = fmaxf(fmaxf(fmaxf(w2[0], w2[1]), fmaxf(w2[2], w2[3])),
                         fmaxf(fmaxf(w2[4], w2[5]), fmaxf(w2[6], w2[7])));
        float nm = fmaxf(m, cm);
        s *= exp2f(m - nm);
        #pragma unroll
        for (int k = 0; k < 8; ++k) s += exp2f(w2[k] - nm);
        m = nm;
    }

    red[tid] = make_float2(m, s);
    __syncthreads();
    if (q == 0) {
        float2 p0 = red[r], p1 = red[64 + r], p2 = red[128 + r], p3 = red[192 + r];
        float M = fmaxf(fmaxf(p0.x, p1.x), fmaxf(p2.x, p3.x));
        float S = p0.y * exp2f(p0.x - M) + p1.y * exp2f(p1.x - M)
                + p2.y * exp2f(p2.x - M) + p3.y * exp2f(p3.x - M);
        dual_out[b * NPTS + row] = K_EPS_LOGMRG + xi.w - K_EPS_LN2 * (M + __log2f(S));
    }
}

// ---------------------------------------------------------------- emd -------
// out[b] = sum_ij P_ij * C_ij,  P = 2^{ (f_i + g_j - C_ij) * R }
__global__ __launch_bounds__(256) void emd_kernel(
    const float4* __restrict__ px, const float4* __restrict__ py,
    const float* __restrict__ f, const float* __restrict__ g,
    float* __restrict__ out)
{
    __shared__ float4 ld[NPTS];
    __shared__ float  vj[NPTS];
    __shared__ float  wsum[4];

    const int w     = blockIdx.x;
    const int b     = w >> 5;
    const int chunk = w & 31;
    const int tid   = threadIdx.x;

    for (int k = tid; k < NPTS; k += 256) {
        float4 p = py[b * NPTS + k];
        ld[k] = p;
        vj[k] = (g[b * NPTS + k] - p.w) * K_R;
    }
    __syncthreads();

    const int r   = tid & 63;
    const int q   = tid >> 6;
    const int row = chunk * 64 + r;
    const float4 xi = px[b * NPTS + row];
    const float u = (f[b * NPTS + row] - xi.w) * K_R;

    float acc = 0.0f;
    const int j0 = q * 512;
    for (int j = j0; j < j0 + 512; ++j) {
        float4 yj = ld[j];
        float dot = fmaf(yj.x, xi.x, fmaf(yj.y, xi.y, yj.z * xi.z));
        float C   = fmaf(-2.0f, dot, xi.w + yj.w);
        float t   = fmaf(K_TWO_R, dot, u + vj[j]);
        acc = fmaf(exp2f(t), C, acc);
    }

    #pragma unroll
    for (int off = 32; off > 0; off >>= 1) acc += __shfl_down(acc, off, 64);
    if (r == 0) wsum[q] = acc;
    __syncthreads();
    if (tid == 0) atomicAdd(&out[b], wsum[0] + wsum[1] + wsum[2] + wsum[3]);
}

// -------------------------------------------------------------- launch ------
extern "C" void kernel_launch(void* const* d_in, const int* in_sizes, int n_in,
                              void* d_out, int out_size, void* d_ws, size_t ws_size,
                              hipStream_t stream)
{
    const float* x = (const float*)d_in[0];
    const float* y = (const float*)d_in[1];
    float* out = (float*)d_out;

    char* ws = (char*)d_ws;
    float4* px = (float4*)(ws);
    float4* py = (float4*)(ws + (size_t)NB * NPTS * 16);
    float*  f  = (float*) (ws + (size_t)NB * NPTS * 32);
    float*  g  = (float*) (ws + (size_t)NB * NPTS * 32 + (size_t)NB * NPTS * 4);

    hipMemsetAsync(d_out, 0, (size_t)out_size * sizeof(float), stream);

    prep_kernel<<<(NB * NPTS + 255) / 256, 256, 0, stream>>>(x, y, px, py, g);

    for (int it = 0; it < 50; ++it) {
        half_step<<<512, 256, 0, stream>>>(py, g, px, f);  // f-update
        half_step<<<512, 256, 0, stream>>>(px, f, py, g);  // g-update
    }

    emd_kernel<<<512, 256, 0, stream>>>(px, py, f, g, out);
}

// Round 2
// 1813.433 us; speedup vs baseline: 1.5286x; 1.5286x over previous
//
#include <hip/hip_runtime.h>

#define NPTS 2048
#define NB   16

// eps = 0.01, log-domain Sinkhorn in base-2.
// R = 1/(eps*ln2); TWO_R = 2R; EPS_LN2 = eps*ln2; EPS_LOGMARG = eps * (-ln N)
constexpr float K_R          = 144.26950408889634f;
constexpr float K_TWO_R      = 288.53900817779268f;
constexpr float K_EPS_LN2    = 0.0069314718055994531f;
constexpr float K_EPS_LOGMRG = -0.076246189861593985f; // 0.01 * (-ln 2048)

__device__ __forceinline__ float fexp2(float x) { return __builtin_amdgcn_exp2f(x); }
__device__ __forceinline__ float flog2(float x) { return __builtin_amdgcn_logf(x); }

// ---------------------------------------------------------------- prep ------
__global__ __launch_bounds__(256) void prep_kernel(
    const float* __restrict__ x, const float* __restrict__ y,
    float4* __restrict__ px, float4* __restrict__ py, float* __restrict__ g)
{
    int idx = blockIdx.x * 256 + threadIdx.x;
    if (idx >= NB * NPTS) return;
    float x0 = x[idx*3+0], x1 = x[idx*3+1], x2 = x[idx*3+2];
    px[idx] = make_float4(x0, x1, x2, fmaf(x0,x0, fmaf(x1,x1, x2*x2)));
    float y0 = y[idx*3+0], y1 = y[idx*3+1], y2 = y[idx*3+2];
    py[idx] = make_float4(y0, y1, y2, fmaf(y0,y0, fmaf(y1,y1, y2*y2)));
    g[idx] = 0.0f;
}

// ------------------------------------------------------------ half step -----
// dual_out[i] = eps*log(1/N) + |p_row_i|^2 - eps*ln2 * log2( sum_j 2^{w2_ij} )
// w2_ij = ( (dual_in_j - |p_col_j|^2) + 2 p_row_i . p_col_j ) / (eps*ln2)
// Grid: 1024 wgs (64 per batch), 256 threads. 32 rows/wg, 8-way j split.
__global__ __launch_bounds__(256) void half_step(
    const float4* __restrict__ pcol, const float* __restrict__ dual_in,
    const float4* __restrict__ prow, float* __restrict__ dual_out)
{
    __shared__ float4 ld[NPTS];     // (y*2R, (dual-|y|^2)*R) packed
    __shared__ float2 red[256];

    const int w     = blockIdx.x;
    const int b     = w >> 6;
    const int chunk = w & 63;
    const int tid   = threadIdx.x;

    const float4* pc = pcol    + b * NPTS;
    const float*  di = dual_in + b * NPTS;

    for (int k = tid; k < NPTS; k += 256) {
        float4 p = pc[k];
        float a2 = (di[k] - p.w) * K_R;
        ld[k] = make_float4(p.x * K_TWO_R, p.y * K_TWO_R, p.z * K_TWO_R, a2);
    }

    const int r   = tid & 31;
    const int q   = tid >> 5;
    const int row = chunk * 32 + r;
    const float4 xi = prow[b * NPTS + row];

    __syncthreads();

    float m = -3.0e38f;
    float s = 0.0f;
    const int j0 = q * 256;
    for (int j = j0; j < j0 + 256; j += 8) {
        float w2[8];
        #pragma unroll
        for (int k = 0; k < 8; ++k) {
            float4 yj = ld[j + k];
            w2[k] = fmaf(yj.x, xi.x, fmaf(yj.y, xi.y, fmaf(yj.z, xi.z, yj.w)));
        }
        float cm = fmaxf(fmaxf(fmaxf(w2[0], w2[1]), fmaxf(w2[2], w2[3])),
                         fmaxf(fmaxf(w2[4], w2[5]), fmaxf(w2[6], w2[7])));
        float nm = fmaxf(m, cm);
        float e0 = fexp2(w2[0] - nm), e1 = fexp2(w2[1] - nm);
        float e2 = fexp2(w2[2] - nm), e3 = fexp2(w2[3] - nm);
        float e4 = fexp2(w2[4] - nm), e5 = fexp2(w2[5] - nm);
        float e6 = fexp2(w2[6] - nm), e7 = fexp2(w2[7] - nm);
        float csum = ((e0 + e1) + (e2 + e3)) + ((e4 + e5) + (e6 + e7));
        s = fmaf(s, fexp2(m - nm), csum);
        m = nm;
    }

    red[tid] = make_float2(m, s);
    __syncthreads();
    if (tid < 32) {
        float M = -3.0e38f;
        #pragma unroll
        for (int qq = 0; qq < 8; ++qq) M = fmaxf(M, red[r + 32*qq].x);
        float S = 0.0f;
        #pragma unroll
        for (int qq = 0; qq < 8; ++qq) {
            float2 p = red[r + 32*qq];
            S += p.y * fexp2(p.x - M);
        }
        dual_out[b * NPTS + row] = K_EPS_LOGMRG + xi.w - K_EPS_LN2 * (M + flog2(S));
    }
}

// ---------------------------------------------------------------- emd -------
// out[b] = sum_ij P_ij * C_ij,  P = 2^{ (f_i + g_j - C_ij) * R }
__global__ __launch_bounds__(256) void emd_kernel(
    const float4* __restrict__ px, const float4* __restrict__ py,
    const float* __restrict__ f, const float* __restrict__ g,
    float* __restrict__ out)
{
    __shared__ float4 ld[NPTS];
    __shared__ float  vj[NPTS];
    __shared__ float  wsum[4];

    const int w     = blockIdx.x;
    const int b     = w >> 6;
    const int chunk = w & 63;
    const int tid   = threadIdx.x;

    for (int k = tid; k < NPTS; k += 256) {
        float4 p = py[b * NPTS + k];
        ld[k] = p;
        vj[k] = (g[b * NPTS + k] - p.w) * K_R;
    }

    const int r   = tid & 31;
    const int q   = tid >> 5;
    const int row = chunk * 32 + r;
    const float4 xi = px[b * NPTS + row];
    const float u = (f[b * NPTS + row] - xi.w) * K_R;

    __syncthreads();

    float acc = 0.0f;
    const int j0 = q * 256;
    for (int j = j0; j < j0 + 256; ++j) {
        float4 yj = ld[j];
        float dot = fmaf(yj.x, xi.x, fmaf(yj.y, xi.y, yj.z * xi.z));
        float C   = fmaf(-2.0f, dot, xi.w + yj.w);
        float t   = fmaf(K_TWO_R, dot, u + vj[j]);
        acc = fmaf(fexp2(t), C, acc);
    }

    // wave-level sum (64 lanes), then combine the 4 waves
    #pragma unroll
    for (int off = 32; off > 0; off >>= 1) acc += __shfl_down(acc, off, 64);
    if ((tid & 63) == 0) wsum[tid >> 6] = acc;
    __syncthreads();
    if (tid == 0) atomicAdd(&out[b], wsum[0] + wsum[1] + wsum[2] + wsum[3]);
}

// -------------------------------------------------------------- launch ------
extern "C" void kernel_launch(void* const* d_in, const int* in_sizes, int n_in,
                              void* d_out, int out_size, void* d_ws, size_t ws_size,
                              hipStream_t stream)
{
    const float* x = (const float*)d_in[0];
    const float* y = (const float*)d_in[1];
    float* out = (float*)d_out;

    char* ws = (char*)d_ws;
    float4* px = (float4*)(ws);
    float4* py = (float4*)(ws + (size_t)NB * NPTS * 16);
    float*  f  = (float*) (ws + (size_t)NB * NPTS * 32);
    float*  g  = (float*) (ws + (size_t)NB * NPTS * 32 + (size_t)NB * NPTS * 4);

    hipMemsetAsync(d_out, 0, (size_t)out_size * sizeof(float), stream);

    prep_kernel<<<(NB * NPTS + 255) / 256, 256, 0, stream>>>(x, y, px, py, g);

    for (int it = 0; it < 50; ++it) {
        half_step<<<1024, 256, 0, stream>>>(py, g, px, f);  // f-update
        half_step<<<1024, 256, 0, stream>>>(px, f, py, g);  // g-update
    }

    emd_kernel<<<1024, 256, 0, stream>>>(px, py, f, g, out);
}

// Round 3
// 1594.984 us; speedup vs baseline: 1.7380x; 1.1370x over previous
//
#include <hip/hip_runtime.h>

#define NPTS 2048
#define NB   16

// eps = 0.01, log-domain Sinkhorn in base-2.
constexpr float K_R          = 144.26950408889634f;   // log2(e)/eps
constexpr float K_TWO_R      = 288.53900817779268f;   // 2*K_R
constexpr float K_EPS_LN2    = 0.0069314718055994531f; // eps*ln2
constexpr float K_EPS_LOGMRG = -0.076246189861593985f; // eps*ln(1/2048)

__device__ __forceinline__ float fexp2(float x) { return __builtin_amdgcn_exp2f(x); }
__device__ __forceinline__ float flog2(float x) { return __builtin_amdgcn_logf(x); }

// ---------------------------------------------------------------- prep ------
__global__ __launch_bounds__(256) void prep_kernel(
    const float* __restrict__ x, const float* __restrict__ y,
    float4* __restrict__ px, float4* __restrict__ py, float* __restrict__ g)
{
    int idx = blockIdx.x * 256 + threadIdx.x;
    if (idx >= NB * NPTS) return;
    float x0 = x[idx*3+0], x1 = x[idx*3+1], x2 = x[idx*3+2];
    px[idx] = make_float4(x0, x1, x2, fmaf(x0,x0, fmaf(x1,x1, x2*x2)));
    float y0 = y[idx*3+0], y1 = y[idx*3+1], y2 = y[idx*3+2];
    py[idx] = make_float4(y0, y1, y2, fmaf(y0,y0, fmaf(y1,y1, y2*y2)));
    g[idx] = 0.0f;
}

// ------------------------------------------------------------ half step -----
// dual_out[i] = eps*log(1/N) - eps*ln2 * log2( S_i ),
//   S_i = sum_j 2^{ (dual_in_j - C_ij) * K_R }   (no max shift: args bounded)
// exponent built as: 2R*(x.y) + (dual_j - |y_j|^2)*R - |x_i|^2*R
// Grid: 1024 wgs (64/batch), 256 thr: 32 rows/wg, 8-way j-split in-wave.
// LDS float4 panel XOR-swizzled by region (slot = j ^ (j>>8)) so the 8
// q-regions' reads per instruction cover all 32 banks (conflict-free).
__global__ __launch_bounds__(256) void half_step(
    const float4* __restrict__ pcol, const float* __restrict__ dual_in,
    const float4* __restrict__ prow, float* __restrict__ dual_out)
{
    __shared__ float4 ld[NPTS];   // (y*2R, (dual-|y|^2)*R), swizzled

    const int b     = blockIdx.x >> 6;
    const int chunk = blockIdx.x & 63;
    const int tid   = threadIdx.x;

    const float4* pc = pcol    + b * NPTS;
    const float*  di = dual_in + b * NPTS;

    #pragma unroll
    for (int it = 0; it < 8; ++it) {
        int k = it * 256 + tid;
        float4 p = pc[k];
        ld[it * 256 + (tid ^ it)] =
            make_float4(p.x * K_TWO_R, p.y * K_TWO_R, p.z * K_TWO_R,
                        (di[k] - p.w) * K_R);
    }

    const int q   = tid & 7;
    const int row = chunk * 32 + (tid >> 3);
    const float4 xi = prow[b * NPTS + row];
    const float  u0 = -xi.w * K_R;

    __syncthreads();

    const float4* base = &ld[q * 256];
    const float4* p0 = base + (q ^ 0);
    const float4* p1 = base + (q ^ 1);
    const float4* p2 = base + (q ^ 2);
    const float4* p3 = base + (q ^ 3);
    const float4* p4 = base + (q ^ 4);
    const float4* p5 = base + (q ^ 5);
    const float4* p6 = base + (q ^ 6);
    const float4* p7 = base + (q ^ 7);

    float a0 = 0.f, a1 = 0.f, a2 = 0.f, a3 = 0.f;
    for (int c = 0; c < 256; c += 8) {
        float4 y0 = p0[c], y1 = p1[c], y2 = p2[c], y3 = p3[c];
        float4 y4 = p4[c], y5 = p5[c], y6 = p6[c], y7 = p7[c];
        float e0 = fexp2(fmaf(y0.x, xi.x, fmaf(y0.y, xi.y, fmaf(y0.z, xi.z, y0.w + u0))));
        float e1 = fexp2(fmaf(y1.x, xi.x, fmaf(y1.y, xi.y, fmaf(y1.z, xi.z, y1.w + u0))));
        float e2 = fexp2(fmaf(y2.x, xi.x, fmaf(y2.y, xi.y, fmaf(y2.z, xi.z, y2.w + u0))));
        float e3 = fexp2(fmaf(y3.x, xi.x, fmaf(y3.y, xi.y, fmaf(y3.z, xi.z, y3.w + u0))));
        float e4 = fexp2(fmaf(y4.x, xi.x, fmaf(y4.y, xi.y, fmaf(y4.z, xi.z, y4.w + u0))));
        float e5 = fexp2(fmaf(y5.x, xi.x, fmaf(y5.y, xi.y, fmaf(y5.z, xi.z, y5.w + u0))));
        float e6 = fexp2(fmaf(y6.x, xi.x, fmaf(y6.y, xi.y, fmaf(y6.z, xi.z, y6.w + u0))));
        float e7 = fexp2(fmaf(y7.x, xi.x, fmaf(y7.y, xi.y, fmaf(y7.z, xi.z, y7.w + u0))));
        a0 += e0; a1 += e1; a2 += e2; a3 += e3;
        a0 += e4; a1 += e5; a2 += e6; a3 += e7;
    }

    float s = (a0 + a1) + (a2 + a3);
    s += __shfl_xor(s, 1, 64);
    s += __shfl_xor(s, 2, 64);
    s += __shfl_xor(s, 4, 64);
    if (q == 0)
        dual_out[b * NPTS + row] = K_EPS_LOGMRG - K_EPS_LN2 * flog2(s);
}

// ---------------------------------------------------------------- emd -------
// out[b] = sum_ij 2^{t} * C,  t = (f_i + g_j - C_ij)*K_R
// ld = (y raw, |y|^2) swizzled by region; hh = (g_j - |y_j|^2)*K_R swizzled
// by region<<2 (so float4 reads of hh are conflict-free across q too).
__global__ __launch_bounds__(256) void emd_kernel(
    const float4* __restrict__ px, const float4* __restrict__ py,
    const float* __restrict__ f, const float* __restrict__ g,
    float* __restrict__ out)
{
    __shared__ float4 ld[NPTS];   // 32768 B
    __shared__ float  hh[NPTS];   //  8192 B  (total 40960 = 160K/4 exact)

    const int b     = blockIdx.x >> 6;
    const int chunk = blockIdx.x & 63;
    const int tid   = threadIdx.x;

    #pragma unroll
    for (int it = 0; it < 8; ++it) {
        int k = it * 256 + tid;
        float4 p = py[b * NPTS + k];
        ld[it * 256 + (tid ^ it)] = p;
        hh[it * 256 + (tid ^ (it << 2))] = (g[b * NPTS + k] - p.w) * K_R;
    }

    const int q   = tid & 7;
    const int row = chunk * 32 + (tid >> 3);
    const float4 xi = px[b * NPTS + row];
    const float  u2 = (f[b * NPTS + row] - xi.w) * K_R;

    __syncthreads();

    const float4* base = &ld[q * 256];
    const float4* p0 = base + (q ^ 0);
    const float4* p1 = base + (q ^ 1);
    const float4* p2 = base + (q ^ 2);
    const float4* p3 = base + (q ^ 3);
    const float4* p4 = base + (q ^ 4);
    const float4* p5 = base + (q ^ 5);
    const float4* p6 = base + (q ^ 6);
    const float4* p7 = base + (q ^ 7);
    const float* hbase = &hh[q * 256];
    const int ho = q << 2;

    float acc0 = 0.f, acc1 = 0.f;
    for (int c = 0; c < 256; c += 8) {
        float4 hv0 = *(const float4*)&hbase[(c    ) ^ ho];  // elems c..c+3
        float4 hv1 = *(const float4*)&hbase[(c + 4) ^ ho];  // elems c+4..c+7
        float4 y0 = p0[c], y1 = p1[c], y2 = p2[c], y3 = p3[c];
        float4 y4 = p4[c], y5 = p5[c], y6 = p6[c], y7 = p7[c];

        float d0 = fmaf(y0.x, xi.x, fmaf(y0.y, xi.y, y0.z * xi.z));
        float d1 = fmaf(y1.x, xi.x, fmaf(y1.y, xi.y, y1.z * xi.z));
        float d2 = fmaf(y2.x, xi.x, fmaf(y2.y, xi.y, y2.z * xi.z));
        float d3 = fmaf(y3.x, xi.x, fmaf(y3.y, xi.y, y3.z * xi.z));
        float d4 = fmaf(y4.x, xi.x, fmaf(y4.y, xi.y, y4.z * xi.z));
        float d5 = fmaf(y5.x, xi.x, fmaf(y5.y, xi.y, y5.z * xi.z));
        float d6 = fmaf(y6.x, xi.x, fmaf(y6.y, xi.y, y6.z * xi.z));
        float d7 = fmaf(y7.x, xi.x, fmaf(y7.y, xi.y, y7.z * xi.z));

        float C0 = fmaf(-2.f, d0, xi.w + y0.w);
        float C1 = fmaf(-2.f, d1, xi.w + y1.w);
        float C2 = fmaf(-2.f, d2, xi.w + y2.w);
        float C3 = fmaf(-2.f, d3, xi.w + y3.w);
        float C4 = fmaf(-2.f, d4, xi.w + y4.w);
        float C5 = fmaf(-2.f, d5, xi.w + y5.w);
        float C6 = fmaf(-2.f, d6, xi.w + y6.w);
        float C7 = fmaf(-2.f, d7, xi.w + y7.w);

        float t0 = fmaf(K_TWO_R, d0, u2 + hv0.x);
        float t1 = fmaf(K_TWO_R, d1, u2 + hv0.y);
        float t2 = fmaf(K_TWO_R, d2, u2 + hv0.z);
        float t3 = fmaf(K_TWO_R, d3, u2 + hv0.w);
        float t4 = fmaf(K_TWO_R, d4, u2 + hv1.x);
        float t5 = fmaf(K_TWO_R, d5, u2 + hv1.y);
        float t6 = fmaf(K_TWO_R, d6, u2 + hv1.z);
        float t7 = fmaf(K_TWO_R, d7, u2 + hv1.w);

        acc0 = fmaf(fexp2(t0), C0, acc0);
        acc1 = fmaf(fexp2(t1), C1, acc1);
        acc0 = fmaf(fexp2(t2), C2, acc0);
        acc1 = fmaf(fexp2(t3), C3, acc1);
        acc0 = fmaf(fexp2(t4), C4, acc0);
        acc1 = fmaf(fexp2(t5), C5, acc1);
        acc0 = fmaf(fexp2(t6), C6, acc0);
        acc1 = fmaf(fexp2(t7), C7, acc1);
    }

    float s = acc0 + acc1;
    #pragma unroll
    for (int off = 1; off < 64; off <<= 1) s += __shfl_xor(s, off, 64);

    __syncthreads();               // panel reads done; reuse ld as scratch
    float* ws = (float*)ld;
    if ((tid & 63) == 0) ws[tid >> 6] = s;
    __syncthreads();
    if (tid == 0) atomicAdd(&out[b], ws[0] + ws[1] + ws[2] + ws[3]);
}

// -------------------------------------------------------------- launch ------
extern "C" void kernel_launch(void* const* d_in, const int* in_sizes, int n_in,
                              void* d_out, int out_size, void* d_ws, size_t ws_size,
                              hipStream_t stream)
{
    const float* x = (const float*)d_in[0];
    const float* y = (const float*)d_in[1];
    float* out = (float*)d_out;

    char* ws = (char*)d_ws;
    float4* px = (float4*)(ws);
    float4* py = (float4*)(ws + (size_t)NB * NPTS * 16);
    float*  f  = (float*) (ws + (size_t)NB * NPTS * 32);
    float*  g  = (float*) (ws + (size_t)NB * NPTS * 32 + (size_t)NB * NPTS * 4);

    hipMemsetAsync(d_out, 0, (size_t)out_size * sizeof(float), stream);

    prep_kernel<<<(NB * NPTS + 255) / 256, 256, 0, stream>>>(x, y, px, py, g);

    for (int it = 0; it < 50; ++it) {
        half_step<<<1024, 256, 0, stream>>>(py, g, px, f);  // f-update
        half_step<<<1024, 256, 0, stream>>>(px, f, py, g);  // g-update
    }

    emd_kernel<<<1024, 256, 0, stream>>>(px, py, f, g, out);
}